// Round 1
// baseline (142.111 us; speedup 1.0000x reference)
//
#include <hip/hip_runtime.h>
#include <stdint.h>

#define LVLS 16
#define TSZ (1u << 19)
#define PR1 2654435761u
#define PR2 805459861u
#define PR3 3674653429u

// ---------------- Kernel A: encode (round-6 version, frozen; ~97us) ----------
// blockIdx round-robins across 8 XCDs: level = (bid%8) + 8*(bid/(8*B)) pins all
// blocks of a level to one XCD (its L2 holds that 4MB slice; FETCH ~= compulsory
// 93MB). 2 threads/point: thread s owns dim-0 corner bit, 8 float2 gathers,
// pair shfl reduce, s==0 writes transposed enc_t[l*N+p].
// Encode is at the random-gather L2-line ceiling (~2.8 TB/s line delivery per
// XCD = 64% of streaming L2 BW) — do not touch.
__global__ __launch_bounds__(256, 8) void encode_kernel(
    const float* __restrict__ img, const float* __restrict__ pose,
    const float* __restrict__ table, float* __restrict__ encbuf,
    int npts, int Bper)
{
    const int bid = blockIdx.x;
    const int grp = 8 * Bper;
    const int level = (bid % 8) + 8 * (bid / grp);
    const int within = (bid % grp) / 8;

    const int idx = within * 256 + threadIdx.x;
    const int p = idx >> 1;
    const int s = idx & 1;
    if (p >= npts) return;

    const float2 xi = ((const float2*)img)[p];
    const float2 xp = ((const float2*)pose)[p];

    constexpr float resv[LVLS] = {16.f, 22.f, 30.f, 42.f, 58.f, 80.f, 110.f, 152.f,
                                  210.f, 290.f, 400.f, 553.f, 763.f, 1053.f, 1453.f, 2005.f};
    const float rr = resv[level];

    const float s0 = xi.x * rr, s1 = xi.y * rr, s2 = xp.x * rr, s3 = xp.y * rr;
    const float p0f = floorf(s0), p1f = floorf(s1), p2f = floorf(s2), p3f = floorf(s3);
    const float f0 = s0 - p0f, f1 = s1 - p1f, f2 = s2 - p2f, f3 = s3 - p3f;
    const uint32_t q0 = (uint32_t)p0f, q1 = (uint32_t)p1f,
                   q2 = (uint32_t)p2f, q3 = (uint32_t)p3f;

    const uint32_t b0  = q0 + (uint32_t)s;
    const uint32_t h1a = q1 * PR1, h1b = h1a + PR1;
    const uint32_t h2a = q2 * PR2, h2b = h2a + PR2;
    const uint32_t h3a = q3 * PR3, h3b = h3a + PR3;
    const uint32_t loff = (uint32_t)level * TSZ;

    const float2* __restrict__ tab2 = (const float2*)table;

    float2 f[8];
    #pragma unroll
    for (int c = 0; c < 8; ++c) {
        const uint32_t h = b0 ^ ((c & 1) ? h1b : h1a)
                              ^ ((c & 2) ? h2b : h2a)
                              ^ ((c & 4) ? h3b : h3a);
        f[c] = tab2[(h & (TSZ - 1u)) + loff];
    }

    const float w0 = s ? f0 : 1.f - f0;
    const float w1a = 1.f - f1, w2a = 1.f - f2, w3a = 1.f - f3;

    float e0 = 0.f, e1 = 0.f;
    #pragma unroll
    for (int c = 0; c < 8; ++c) {
        const float w = w0 * ((c & 1) ? f1 : w1a)
                           * ((c & 2) ? f2 : w2a)
                           * ((c & 4) ? f3 : w3a);
        e0 = fmaf(w, f[c].x, e0);
        e1 = fmaf(w, f[c].y, e1);
    }

    e0 += __shfl_xor(e0, 1);
    e1 += __shfl_xor(e1, 1);

    if (s == 0)
        ((float2*)encbuf)[(size_t)level * npts + p] = make_float2(e0, e1);
}

// ---------------- Kernel B: MLP, thread-per-point, no LDS, no barriers -------
// Round-7 rewrite. Each thread owns one point end-to-end: h1[64] and h2[64]
// live in registers (fully unrolled — compile-time indices only, runtime
// indexing would spill to scratch). All weight reads are wave-uniform ->
// s_load on the scalar pipe (zero VALU issue cost). Removes the previous
// version's 3 syncthreads, 128 ds_read/thread h1 exchange, 4x-redundant enc
// reads, and the 3-idle-wave reduction epilogue. Total work = 2048 waves =
// 2 waves/SIMD, so the ~150-VGPR footprint costs no occupancy we could use.
// Issue floor: 6720 FMA/point -> 11.2us; predict ~12-14us (was ~21us).
__global__ __launch_bounds__(256, 2) void mlp_kernel(
    const float* __restrict__ encbuf, const float* __restrict__ W1,
    const float* __restrict__ W2, const float* __restrict__ W3,
    float* __restrict__ out, int npts)
{
    const int p = blockIdx.x * 256 + threadIdx.x;
    if (p >= npts) return;

    const float2* __restrict__ e2 = (const float2*)encbuf;

    // ---- h1 = relu(enc @ W1): stream enc level-by-level (coalesced 8B/lane)
    float h[64];
    #pragma unroll
    for (int j = 0; j < 64; ++j) h[j] = 0.f;
    #pragma unroll
    for (int l = 0; l < LVLS; ++l) {
        const float2 e = e2[(size_t)l * npts + p];
        #pragma unroll
        for (int j = 0; j < 64; ++j) {
            h[j] = fmaf(e.x, W1[(2 * l) * 64 + j], h[j]);
            h[j] = fmaf(e.y, W1[(2 * l + 1) * 64 + j], h[j]);
        }
    }
    #pragma unroll
    for (int j = 0; j < 64; ++j) h[j] = fmaxf(h[j], 0.f);

    // ---- h2 = relu(h1 @ W2)
    float g[64];
    #pragma unroll
    for (int j = 0; j < 64; ++j) g[j] = 0.f;
    #pragma unroll
    for (int i = 0; i < 64; ++i) {
        const float hi = h[i];
        #pragma unroll
        for (int j = 0; j < 64; ++j)
            g[j] = fmaf(hi, W2[i * 64 + j], g[j]);
    }

    // ---- out = h2 @ W3 (relu fused into the read of g)
    float o[9];
    #pragma unroll
    for (int k = 0; k < 9; ++k) o[k] = 0.f;
    #pragma unroll
    for (int j = 0; j < 64; ++j) {
        const float gj = fmaxf(g[j], 0.f);
        #pragma unroll
        for (int k = 0; k < 9; ++k)
            o[k] = fmaf(gj, W3[j * 9 + k], o[k]);
    }

    float* dst = out + (size_t)9 * p;
    #pragma unroll
    for (int k = 0; k < 9; ++k) dst[k] = o[k];
}

// ---------------- Fallback: fused single kernel (round-1, known-good) ----------------
__global__ __launch_bounds__(256) void hashgrid_mlp_kernel(
    const float* __restrict__ img, const float* __restrict__ pose,
    const float* __restrict__ table, const float* __restrict__ W1,
    const float* __restrict__ W2, const float* __restrict__ W3,
    float* __restrict__ out)
{
    const int n = blockIdx.x * 256 + threadIdx.x;

    const float x0 = img[2 * n], x1 = img[2 * n + 1];
    const float x2 = pose[2 * n], x3 = pose[2 * n + 1];

    const float resv[LVLS] = {16.f, 22.f, 30.f, 42.f, 58.f, 80.f, 110.f, 152.f,
                              210.f, 290.f, 400.f, 553.f, 763.f, 1053.f, 1453.f, 2005.f};

    const float2* __restrict__ tab2 = (const float2*)table;

    float enc[32];

    #pragma unroll
    for (int l = 0; l < LVLS; ++l) {
        const float r = resv[l];
        const float s0 = x0 * r, s1 = x1 * r, s2 = x2 * r, s3 = x3 * r;
        const float p0 = floorf(s0), p1 = floorf(s1), p2 = floorf(s2), p3 = floorf(s3);
        const float f0 = s0 - p0, f1 = s1 - p1, f2 = s2 - p2, f3 = s3 - p3;
        const uint32_t q0 = (uint32_t)p0, q1 = (uint32_t)p1,
                       q2 = (uint32_t)p2, q3 = (uint32_t)p3;

        const uint32_t h1a = q1 * PR1, h1b = h1a + PR1;
        const uint32_t h2a = q2 * PR2, h2b = h2a + PR2;
        const uint32_t h3a = q3 * PR3, h3b = h3a + PR3;
        const float w0a = 1.f - f0, w1a = 1.f - f1, w2a = 1.f - f2, w3a = 1.f - f3;

        float2 feat[16];
        #pragma unroll
        for (int c = 0; c < 16; ++c) {
            const uint32_t h = (q0 + (c & 1))
                             ^ ((c & 2) ? h1b : h1a)
                             ^ ((c & 4) ? h2b : h2a)
                             ^ ((c & 8) ? h3b : h3a);
            const uint32_t idx = (h & (TSZ - 1u)) + (uint32_t)l * TSZ;
            feat[c] = tab2[idx];
        }

        float e0 = 0.f, e1 = 0.f;
        #pragma unroll
        for (int c = 0; c < 16; ++c) {
            const float w = ((c & 1) ? f0 : w0a) * ((c & 2) ? f1 : w1a)
                          * ((c & 4) ? f2 : w2a) * ((c & 8) ? f3 : w3a);
            e0 = fmaf(w, feat[c].x, e0);
            e1 = fmaf(w, feat[c].y, e1);
        }
        enc[2 * l]     = e0;
        enc[2 * l + 1] = e1;
    }

    float h1[64];
    #pragma unroll
    for (int j = 0; j < 64; ++j) h1[j] = 0.f;
    #pragma unroll
    for (int i = 0; i < 32; ++i) {
        const float e = enc[i];
        #pragma unroll
        for (int j = 0; j < 64; ++j) h1[j] = fmaf(e, W1[i * 64 + j], h1[j]);
    }
    #pragma unroll
    for (int j = 0; j < 64; ++j) h1[j] = fmaxf(h1[j], 0.f);

    float h2[64];
    #pragma unroll
    for (int j = 0; j < 64; ++j) h2[j] = 0.f;
    #pragma unroll
    for (int i = 0; i < 64; ++i) {
        const float e = h1[i];
        #pragma unroll
        for (int j = 0; j < 64; ++j) h2[j] = fmaf(e, W2[i * 64 + j], h2[j]);
    }
    #pragma unroll
    for (int j = 0; j < 64; ++j) h2[j] = fmaxf(h2[j], 0.f);

    float o[9];
    #pragma unroll
    for (int j = 0; j < 9; ++j) o[j] = 0.f;
    #pragma unroll
    for (int i = 0; i < 64; ++i) {
        const float e = h2[i];
        #pragma unroll
        for (int j = 0; j < 9; ++j) o[j] = fmaf(e, W3[i * 9 + j], o[j]);
    }
    #pragma unroll
    for (int j = 0; j < 9; ++j) out[9 * n + j] = o[j];
}

extern "C" void kernel_launch(void* const* d_in, const int* in_sizes, int n_in,
                              void* d_out, int out_size, void* d_ws, size_t ws_size,
                              hipStream_t stream) {
    const float* img   = (const float*)d_in[0];
    const float* pose  = (const float*)d_in[1];
    const float* table = (const float*)d_in[2];
    const float* W1    = (const float*)d_in[3];
    const float* W2    = (const float*)d_in[4];
    const float* W3    = (const float*)d_in[5];
    float* out = (float*)d_out;

    const int n = in_sizes[0] / 2;              // number of points
    const size_t need = (size_t)n * 32 * sizeof(float);

    if (ws_size >= need && (n % 128) == 0 && ((n * 2) % 256) == 0) {
        float* encbuf = (float*)d_ws;
        const int Bper = (n * 2) / 256;         // blocks per level
        hipLaunchKernelGGL(encode_kernel, dim3(Bper * LVLS), dim3(256), 0, stream,
                           img, pose, table, encbuf, n, Bper);
        hipLaunchKernelGGL(mlp_kernel, dim3((n + 255) / 256), dim3(256), 0, stream,
                           encbuf, W1, W2, W3, out, n);
    } else {
        hipLaunchKernelGGL(hashgrid_mlp_kernel, dim3((n + 255) / 256), dim3(256), 0, stream,
                           img, pose, table, W1, W2, W3, out);
    }
}

// Round 2
// 120.089 us; speedup vs baseline: 1.1834x; 1.1834x over previous
//
#include <hip/hip_runtime.h>
#include <stdint.h>

#define LVLS 16
#define TSZ (1u << 19)
#define PR1 2654435761u
#define PR2 805459861u
#define PR3 3674653429u

// ---------------- Kernel A: encode (round-6 version, frozen; ~97us) ----------
// blockIdx round-robins across 8 XCDs: level = (bid%8) + 8*(bid/(8*B)) pins all
// blocks of a level to one XCD (its L2 holds that 4MB slice; FETCH ~= compulsory
// 93MB). 2 threads/point: thread s owns dim-0 corner bit, 8 float2 gathers,
// pair shfl reduce, s==0 writes transposed enc_t[l*N+p].
// Encode is at the random-gather L2-line ceiling — do not touch.
__global__ __launch_bounds__(256, 8) void encode_kernel(
    const float* __restrict__ img, const float* __restrict__ pose,
    const float* __restrict__ table, float* __restrict__ encbuf,
    int npts, int Bper)
{
    const int bid = blockIdx.x;
    const int grp = 8 * Bper;
    const int level = (bid % 8) + 8 * (bid / grp);
    const int within = (bid % grp) / 8;

    const int idx = within * 256 + threadIdx.x;
    const int p = idx >> 1;
    const int s = idx & 1;
    if (p >= npts) return;

    const float2 xi = ((const float2*)img)[p];
    const float2 xp = ((const float2*)pose)[p];

    constexpr float resv[LVLS] = {16.f, 22.f, 30.f, 42.f, 58.f, 80.f, 110.f, 152.f,
                                  210.f, 290.f, 400.f, 553.f, 763.f, 1053.f, 1453.f, 2005.f};
    const float rr = resv[level];

    const float s0 = xi.x * rr, s1 = xi.y * rr, s2 = xp.x * rr, s3 = xp.y * rr;
    const float p0f = floorf(s0), p1f = floorf(s1), p2f = floorf(s2), p3f = floorf(s3);
    const float f0 = s0 - p0f, f1 = s1 - p1f, f2 = s2 - p2f, f3 = s3 - p3f;
    const uint32_t q0 = (uint32_t)p0f, q1 = (uint32_t)p1f,
                   q2 = (uint32_t)p2f, q3 = (uint32_t)p3f;

    const uint32_t b0  = q0 + (uint32_t)s;
    const uint32_t h1a = q1 * PR1, h1b = h1a + PR1;
    const uint32_t h2a = q2 * PR2, h2b = h2a + PR2;
    const uint32_t h3a = q3 * PR3, h3b = h3a + PR3;
    const uint32_t loff = (uint32_t)level * TSZ;

    const float2* __restrict__ tab2 = (const float2*)table;

    float2 f[8];
    #pragma unroll
    for (int c = 0; c < 8; ++c) {
        const uint32_t h = b0 ^ ((c & 1) ? h1b : h1a)
                              ^ ((c & 2) ? h2b : h2a)
                              ^ ((c & 4) ? h3b : h3a);
        f[c] = tab2[(h & (TSZ - 1u)) + loff];
    }

    const float w0 = s ? f0 : 1.f - f0;
    const float w1a = 1.f - f1, w2a = 1.f - f2, w3a = 1.f - f3;

    float e0 = 0.f, e1 = 0.f;
    #pragma unroll
    for (int c = 0; c < 8; ++c) {
        const float w = w0 * ((c & 1) ? f1 : w1a)
                           * ((c & 2) ? f2 : w2a)
                           * ((c & 4) ? f3 : w3a);
        e0 = fmaf(w, f[c].x, e0);
        e1 = fmaf(w, f[c].y, e1);
    }

    e0 += __shfl_xor(e0, 1);
    e1 += __shfl_xor(e1, 1);

    if (s == 0)
        ((float2*)encbuf)[(size_t)level * npts + p] = make_float2(e0, e1);
}

// ---------------- Kernel B: MLP v3 — round-6 structure + float2 exchange -----
// Block = 256 threads = 4 waves, 128 points. Lane owns point-pair (pA=base+lane,
// pB=pA+64); wave w owns columns [16w,16w+16) of h1 AND h2 (keeps per-chunk
// scalar-weight footprint at 16-32 SGPRs -> all weight reads stay s_load; this
// is why thread-per-point failed: 64-128-float rows blow the 102-SGPR budget).
// Changes vs round-6 (21us):
//  * h1 exchanged as float2 point-pairs: 64 ds_read_b64 + 16 ds_write_b64 per
//    lane instead of 128 b32 reads + 32 b32 writes (half the LDS issues; 64
//    lanes x 8B = 512B row = 2-way free bank pattern).
//  * epilogue distributed: all 4 waves write float2 partials, all 256 threads
//    reduce flat slices (coalesced stores) — no 3-idle-wave serial tail.
//  * LDS stays 32KB (oS reuses h1P region behind a barrier) so occupancy
//    stays 4 blocks/CU.
__global__ __launch_bounds__(256, 4) void mlp_kernel(
    const float* __restrict__ encbuf, const float* __restrict__ W1,
    const float* __restrict__ W2, const float* __restrict__ W3,
    float* __restrict__ out, int npts)
{
    __shared__ __align__(16) char ldsbuf[64 * 64 * sizeof(float2)];   // 32 KB
    float2 (*h1P)[64]   = (float2 (*)[64])ldsbuf;      // [64 rows][64 pt-pairs]
    float2 (*oS)[64][9] = (float2 (*)[64][9])ldsbuf;   // [4][64][9] (reuse, 18KB)

    const int lane = threadIdx.x & 63;
    const int w    = __builtin_amdgcn_readfirstlane(threadIdx.x >> 6);   // 0..3
    const int base = blockIdx.x * 128;
    const int pA   = base + lane;
    const int pB   = pA + 64;

    // ---- h1: own 16 columns, both points ----
    const float* __restrict__ W1w = W1 + 16 * w;
    float hA[16], hB[16];
    #pragma unroll
    for (int j = 0; j < 16; ++j) { hA[j] = 0.f; hB[j] = 0.f; }
    const float2* e2 = (const float2*)encbuf;
    #pragma unroll
    for (int l = 0; l < LVLS; ++l) {
        const float2 eA = e2[(size_t)l * npts + pA];
        const float2 eB = e2[(size_t)l * npts + pB];
        #pragma unroll
        for (int j = 0; j < 16; ++j) {
            const float w0 = W1w[(2 * l) * 64 + j];
            const float w1 = W1w[(2 * l + 1) * 64 + j];
            hA[j] = fmaf(eA.x, w0, hA[j]); hA[j] = fmaf(eA.y, w1, hA[j]);
            hB[j] = fmaf(eB.x, w0, hB[j]); hB[j] = fmaf(eB.y, w1, hB[j]);
        }
    }
    #pragma unroll
    for (int j = 0; j < 16; ++j)
        h1P[16 * w + j][lane] = make_float2(fmaxf(hA[j], 0.f), fmaxf(hB[j], 0.f));
    __syncthreads();

    // ---- h2: own 16 columns over all 64 h1 rows, both points (b64 reads) ----
    const float* __restrict__ W2w = W2 + 16 * w;
    float gA[16], gB[16];
    #pragma unroll
    for (int j = 0; j < 16; ++j) { gA[j] = 0.f; gB[j] = 0.f; }
    #pragma unroll
    for (int i = 0; i < 64; ++i) {
        const float2 hv = h1P[i][lane];
        #pragma unroll
        for (int j = 0; j < 16; ++j) {
            const float wv = W2w[i * 64 + j];
            gA[j] = fmaf(hv.x, wv, gA[j]);
            gB[j] = fmaf(hv.y, wv, gB[j]);
        }
    }
    #pragma unroll
    for (int j = 0; j < 16; ++j) { gA[j] = fmaxf(gA[j], 0.f); gB[j] = fmaxf(gB[j], 0.f); }

    // ---- partial o[9] over own 16 h2 rows, both points ----
    const float* __restrict__ W3w = W3 + (16 * w) * 9;
    float oA[9], oB[9];
    #pragma unroll
    for (int k = 0; k < 9; ++k) { oA[k] = 0.f; oB[k] = 0.f; }
    #pragma unroll
    for (int j = 0; j < 16; ++j) {
        #pragma unroll
        for (int k = 0; k < 9; ++k) {
            const float wv = W3w[j * 9 + k];
            oA[k] = fmaf(gA[j], wv, oA[k]);
            oB[k] = fmaf(gB[j], wv, oB[k]);
        }
    }

    __syncthreads();   // h1P no longer needed; safe to reuse region as oS

    #pragma unroll
    for (int k = 0; k < 9; ++k)
        oS[w][lane][k] = make_float2(oA[k], oB[k]);
    __syncthreads();

    // ---- distributed reduce + store: 576 float2 outputs over 256 threads ----
    for (int t = threadIdx.x; t < 576; t += 256) {
        const int p = t / 9;
        const int k = t - 9 * p;
        const float2 s0 = oS[0][p][k];
        const float2 s1 = oS[1][p][k];
        const float2 s2 = oS[2][p][k];
        const float2 s3 = oS[3][p][k];
        const float sx = (s0.x + s1.x) + (s2.x + s3.x);
        const float sy = (s0.y + s1.y) + (s2.y + s3.y);
        out[(size_t)9 * (base + p) + k]      = sx;
        out[(size_t)9 * (base + p + 64) + k] = sy;
    }
}

// ---------------- Fallback: fused single kernel (round-1, known-good) ----------------
__global__ __launch_bounds__(256) void hashgrid_mlp_kernel(
    const float* __restrict__ img, const float* __restrict__ pose,
    const float* __restrict__ table, const float* __restrict__ W1,
    const float* __restrict__ W2, const float* __restrict__ W3,
    float* __restrict__ out)
{
    const int n = blockIdx.x * 256 + threadIdx.x;

    const float x0 = img[2 * n], x1 = img[2 * n + 1];
    const float x2 = pose[2 * n], x3 = pose[2 * n + 1];

    const float resv[LVLS] = {16.f, 22.f, 30.f, 42.f, 58.f, 80.f, 110.f, 152.f,
                              210.f, 290.f, 400.f, 553.f, 763.f, 1053.f, 1453.f, 2005.f};

    const float2* __restrict__ tab2 = (const float2*)table;

    float enc[32];

    #pragma unroll
    for (int l = 0; l < LVLS; ++l) {
        const float r = resv[l];
        const float s0 = x0 * r, s1 = x1 * r, s2 = x2 * r, s3 = x3 * r;
        const float p0 = floorf(s0), p1 = floorf(s1), p2 = floorf(s2), p3 = floorf(s3);
        const float f0 = s0 - p0, f1 = s1 - p1, f2 = s2 - p2, f3 = s3 - p3;
        const uint32_t q0 = (uint32_t)p0, q1 = (uint32_t)p1,
                       q2 = (uint32_t)p2, q3 = (uint32_t)p3;

        const uint32_t h1a = q1 * PR1, h1b = h1a + PR1;
        const uint32_t h2a = q2 * PR2, h2b = h2a + PR2;
        const uint32_t h3a = q3 * PR3, h3b = h3a + PR3;
        const float w0a = 1.f - f0, w1a = 1.f - f1, w2a = 1.f - f2, w3a = 1.f - f3;

        float2 feat[16];
        #pragma unroll
        for (int c = 0; c < 16; ++c) {
            const uint32_t h = (q0 + (c & 1))
                             ^ ((c & 2) ? h1b : h1a)
                             ^ ((c & 4) ? h2b : h2a)
                             ^ ((c & 8) ? h3b : h3a);
            const uint32_t idx = (h & (TSZ - 1u)) + (uint32_t)l * TSZ;
            feat[c] = tab2[idx];
        }

        float e0 = 0.f, e1 = 0.f;
        #pragma unroll
        for (int c = 0; c < 16; ++c) {
            const float w = ((c & 1) ? f0 : w0a) * ((c & 2) ? f1 : w1a)
                          * ((c & 4) ? f2 : w2a) * ((c & 8) ? f3 : w3a);
            e0 = fmaf(w, feat[c].x, e0);
            e1 = fmaf(w, feat[c].y, e1);
        }
        enc[2 * l]     = e0;
        enc[2 * l + 1] = e1;
    }

    float h1[64];
    #pragma unroll
    for (int j = 0; j < 64; ++j) h1[j] = 0.f;
    #pragma unroll
    for (int i = 0; i < 32; ++i) {
        const float e = enc[i];
        #pragma unroll
        for (int j = 0; j < 64; ++j) h1[j] = fmaf(e, W1[i * 64 + j], h1[j]);
    }
    #pragma unroll
    for (int j = 0; j < 64; ++j) h1[j] = fmaxf(h1[j], 0.f);

    float h2[64];
    #pragma unroll
    for (int j = 0; j < 64; ++j) h2[j] = 0.f;
    #pragma unroll
    for (int i = 0; i < 64; ++i) {
        const float e = h1[i];
        #pragma unroll
        for (int j = 0; j < 64; ++j) h2[j] = fmaf(e, W2[i * 64 + j], h2[j]);
    }
    #pragma unroll
    for (int j = 0; j < 64; ++j) h2[j] = fmaxf(h2[j], 0.f);

    float o[9];
    #pragma unroll
    for (int j = 0; j < 9; ++j) o[j] = 0.f;
    #pragma unroll
    for (int i = 0; i < 64; ++i) {
        const float e = h2[i];
        #pragma unroll
        for (int j = 0; j < 9; ++j) o[j] = fmaf(e, W3[i * 9 + j], o[j]);
    }
    #pragma unroll
    for (int j = 0; j < 9; ++j) out[9 * n + j] = o[j];
}

extern "C" void kernel_launch(void* const* d_in, const int* in_sizes, int n_in,
                              void* d_out, int out_size, void* d_ws, size_t ws_size,
                              hipStream_t stream) {
    const float* img   = (const float*)d_in[0];
    const float* pose  = (const float*)d_in[1];
    const float* table = (const float*)d_in[2];
    const float* W1    = (const float*)d_in[3];
    const float* W2    = (const float*)d_in[4];
    const float* W3    = (const float*)d_in[5];
    float* out = (float*)d_out;

    const int n = in_sizes[0] / 2;              // number of points
    const size_t need = (size_t)n * 32 * sizeof(float);

    if (ws_size >= need && (n % 128) == 0 && ((n * 2) % 256) == 0) {
        float* encbuf = (float*)d_ws;
        const int Bper = (n * 2) / 256;         // blocks per level
        hipLaunchKernelGGL(encode_kernel, dim3(Bper * LVLS), dim3(256), 0, stream,
                           img, pose, table, encbuf, n, Bper);
        hipLaunchKernelGGL(mlp_kernel, dim3(n / 128), dim3(256), 0, stream,
                           encbuf, W1, W2, W3, out, n);
    } else {
        hipLaunchKernelGGL(hashgrid_mlp_kernel, dim3((n + 255) / 256), dim3(256), 0, stream,
                           img, pose, table, W1, W2, W3, out);
    }
}